// Round 2
// baseline (317.485 us; speedup 1.0000x reference)
//
#include <hip/hip_runtime.h>

// PadWithin: out[b,c,2i,2j] = feats[b,c,i,j], all other entries zero.
// feats: (16,64,128,128) fp32 -> out: (16,64,256,256) fp32.
//
// R2: grid-stride with 8 iterations/thread. Stride (2,097,152 float4s)
// steps the output row by 32768, so (row & 255) is invariant per thread:
// a wave is all-even-row or all-odd-row for its whole lifetime (uniform
// branch), and the unrolled body gives 8 independent loads + 8 independent
// 16B stores in flight (vs 1 store/thread in R1, which ran latency-bound
// at ~2.5 TB/s while the harness fill kernel hits 6.5 TB/s).

#define THREADS 256
#define BLOCKS 8192
#define TOTAL_VEC4 16777216u                 // 16*64*256*256 / 4
#define STRIDE (BLOCKS * THREADS)            // 2,097,152
#define ITERS (TOTAL_VEC4 / STRIDE)          // 8

__global__ __launch_bounds__(256) void pad_within_kernel(
    const float* __restrict__ in, float* __restrict__ out) {
    unsigned v0 = blockIdx.x * THREADS + threadIdx.x;
    float4* o4 = (float4*)out;

    unsigned row0 = v0 >> 6;        // output row of first iteration
    unsigned oh   = row0 & 255u;    // invariant across iterations (stride % 256 rows == 0)

    if (oh & 1u) {
        // odd output rows: all zeros, 8 independent 16B stores
        const float4 z = make_float4(0.f, 0.f, 0.f, 0.f);
#pragma unroll
        for (int k = 0; k < (int)ITERS; ++k) {
            o4[v0 + (unsigned)k * STRIDE] = z;
        }
    } else {
        // even output rows: out cols (4c..4c+3) <- (in[2c], 0, in[2c+1], 0)
        unsigned ih = oh >> 1;  // invariant
        float2 x[ITERS];
#pragma unroll
        for (int k = 0; k < (int)ITERS; ++k) {
            unsigned v    = v0 + (unsigned)k * STRIDE;
            unsigned col4 = v & 63u;     // float4 index within output row
            unsigned bc   = v >> 14;     // (row >> 8): b*C + c
            const float2* irow = (const float2*)(in + ((size_t)(bc * 128u + ih)) * 128u);
            x[k] = irow[col4];
        }
#pragma unroll
        for (int k = 0; k < (int)ITERS; ++k) {
            unsigned v = v0 + (unsigned)k * STRIDE;
            o4[v] = make_float4(x[k].x, 0.f, x[k].y, 0.f);
        }
    }
}

extern "C" void kernel_launch(void* const* d_in, const int* in_sizes, int n_in,
                              void* d_out, int out_size, void* d_ws, size_t ws_size,
                              hipStream_t stream) {
    const float* feats = (const float*)d_in[0];
    float* out = (float*)d_out;
    pad_within_kernel<<<dim3(BLOCKS), dim3(THREADS), 0, stream>>>(feats, out);
}